// Round 17
// baseline (500.002 us; speedup 1.0000x reference)
//
#include <hip/hip_runtime.h>
#include <math.h>

namespace {
constexpr int NPTS = 1 << 21;
constexpr int NLVL = 16;
constexpr unsigned TMASK = 0x7FFFFu;  // all hashed levels have size T = 2^19
constexpr unsigned PI1 = 2654435761u;
constexpr unsigned PI2 = 805459861u;
constexpr int BLK = 512;
constexpr int PTS_PER_BLK = 512;          // 1 pt/thread (r14-validated)
constexpr int NBLK = NPTS / PTS_PER_BLK;  // 4096
constexpr int NGRID = 7;                  // levels 0..6 grid-indexed
constexpr int NHASH = 9;                  // levels 7..15 hashed, size 2^19
constexpr int BRES = 32;                  // sort bucket grid (r17: 64 -> 32)
constexpr int NBKT = BRES * BRES * BRES;  // 32768

typedef float f2 __attribute__((ext_vector_type(2)));
typedef float f4 __attribute__((ext_vector_type(4)));
typedef unsigned u4 __attribute__((ext_vector_type(4)));

struct Params {
  float resf[NLVL];
  int off[NLVL];        // entry offsets into emb (f2 units)
  int cellOffB[NGRID];  // byte offsets of bf16 cell tables in ws
  int hOffB[NHASH];     // byte offsets of bf16 hashed tables in ws
  unsigned* cnt;        // bucket counters (zeroed by repack_all slice 16)
};

__device__ __forceinline__ int swz(int pt) { return (pt ^ (pt >> 3)) & 7; }

__device__ __forceinline__ unsigned bfrne(float x) {  // f32 -> bf16 bits, RNE
  unsigned f = __float_as_uint(x);
  return (f + 0x7FFFu + ((f >> 16) & 1u)) >> 16;
}
__device__ __forceinline__ unsigned packbf(f2 e) {
  return bfrne(e.x) | (bfrne(e.y) << 16);
}
__device__ __forceinline__ float bflo(unsigned u) {
  return __uint_as_float(u << 16);
}
__device__ __forceinline__ float bfhi(unsigned u) {
  return __uint_as_float(u & 0xFFFF0000u);
}
__device__ __forceinline__ unsigned sel4(f4 v, int k) {
  float g = (k & 2) ? ((k & 1) ? v.w : v.z) : ((k & 1) ? v.y : v.x);
  return __float_as_uint(g);
}
__device__ __forceinline__ int bucket_of(float cx, float cy, float cz) {
  return (int)(cx * 32.f) + ((int)(cy * 32.f) << 5) + ((int)(cz * 32.f) << 10);
}
}  // namespace

// ---- fused repack (r14-validated) + counter zeroing ------------------------
// y=0..6: grid cell-major bf16 (32 B/cell). y=7..15: hashed flat bf16 copy.
// y=16: zero the 32K sort counters (runs strictly before hist_k by stream
// order; intra-kernel slices are independent).
__global__ __launch_bounds__(256) void repack_all(const f2* __restrict__ emb,
                                                  char* __restrict__ ws,
                                                  Params p) {
  int y = (int)blockIdx.y;
  int t = (int)blockIdx.x * 256 + (int)threadIdx.x;  // < 524288
  if (y == NLVL) {  // counter zero slice
    if (t < NBKT) p.cnt[t] = 0u;
    return;
  }
  if (y >= NGRID) {
    int h = y - NGRID;  // static-index chain (rule #20)
    int off = p.off[7], hob = p.hOffB[0];
    if (h == 1) { off = p.off[8]; hob = p.hOffB[1]; }
    if (h == 2) { off = p.off[9]; hob = p.hOffB[2]; }
    if (h == 3) { off = p.off[10]; hob = p.hOffB[3]; }
    if (h == 4) { off = p.off[11]; hob = p.hOffB[4]; }
    if (h == 5) { off = p.off[12]; hob = p.hOffB[5]; }
    if (h == 6) { off = p.off[13]; hob = p.hOffB[6]; }
    if (h == 7) { off = p.off[14]; hob = p.hOffB[7]; }
    if (h == 8) { off = p.off[15]; hob = p.hOffB[8]; }
    ((unsigned*)(ws + (size_t)hob))[t] = packbf(emb[off + t]);
    return;
  }
  float rf = p.resf[0];  // static-index chain
  int off = p.off[0], cob = p.cellOffB[0];
  if (y == 1) { rf = p.resf[1]; off = p.off[1]; cob = p.cellOffB[1]; }
  if (y == 2) { rf = p.resf[2]; off = p.off[2]; cob = p.cellOffB[2]; }
  if (y == 3) { rf = p.resf[3]; off = p.off[3]; cob = p.cellOffB[3]; }
  if (y == 4) { rf = p.resf[4]; off = p.off[4]; cob = p.cellOffB[4]; }
  if (y == 5) { rf = p.resf[5]; off = p.off[5]; cob = p.cellOffB[5]; }
  if (y == 6) { rf = p.resf[6]; off = p.off[6]; cob = p.cellOffB[6]; }
  int res = (int)rf;
  if (t >= res * res * res) return;
  int x = t % res, q = t / res, yy = q % res, z = q / res;
  int s = res + 1, s2 = s * s;
  const f2* base = emb + off + (x + yy * s + z * s2);
  u4 d0, d1;  // corner order j = dx + 2*dy + 4*dz (validated r3-r16)
  d0.x = packbf(base[0]);       d0.y = packbf(base[1]);
  d0.z = packbf(base[s]);       d0.w = packbf(base[s + 1]);
  d1.x = packbf(base[s2]);      d1.y = packbf(base[s2 + 1]);
  d1.z = packbf(base[s2 + s]);  d1.w = packbf(base[s2 + s + 1]);
  u4* dst = (u4*)(ws + (size_t)cob + (size_t)t * 32);
  dst[0] = d0; dst[1] = d1;
}

// ---- legacy grid repack (mode-1 fallback tier only) ------------------------
__global__ __launch_bounds__(256) void repack_grid(const f2* __restrict__ emb,
                                                   char* __restrict__ ws,
                                                   Params p) {
  int lvl = (int)blockIdx.y;
  float rf = p.resf[0];
  int off = p.off[0], cob = p.cellOffB[0];
  if (lvl == 1) { rf = p.resf[1]; off = p.off[1]; cob = p.cellOffB[1]; }
  if (lvl == 2) { rf = p.resf[2]; off = p.off[2]; cob = p.cellOffB[2]; }
  if (lvl == 3) { rf = p.resf[3]; off = p.off[3]; cob = p.cellOffB[3]; }
  if (lvl == 4) { rf = p.resf[4]; off = p.off[4]; cob = p.cellOffB[4]; }
  if (lvl == 5) { rf = p.resf[5]; off = p.off[5]; cob = p.cellOffB[5]; }
  if (lvl == 6) { rf = p.resf[6]; off = p.off[6]; cob = p.cellOffB[6]; }
  int res = (int)rf;
  int t = (int)blockIdx.x * 256 + (int)threadIdx.x;
  if (t >= res * res * res) return;
  int x = t % res, q = t / res, y = q % res, z = q / res;
  int s = res + 1, s2 = s * s;
  const f2* base = emb + off + (x + y * s + z * s2);
  u4 d0, d1;
  d0.x = packbf(base[0]);       d0.y = packbf(base[1]);
  d0.z = packbf(base[s]);       d0.w = packbf(base[s + 1]);
  d1.x = packbf(base[s2]);      d1.y = packbf(base[s2 + 1]);
  d1.z = packbf(base[s2 + s]);  d1.w = packbf(base[s2 + s + 1]);
  u4* dst = (u4*)(ws + (size_t)cob + (size_t)t * 32);
  dst[0] = d0; dst[1] = d1;
}

// ---- bucket-sort pipeline (r13/r14-validated; order-independent values) ----
__global__ __launch_bounds__(256) void hist_k(const float* __restrict__ coords,
                                              unsigned* __restrict__ cnt) {
  int t = (int)blockIdx.x * 256 + (int)threadIdx.x;  // < NPTS/4
  const f4* C = (const f4*)(coords + (size_t)t * 12);
  f4 a = C[0], b = C[1], c = C[2];
  atomicAdd(&cnt[bucket_of(a.x, a.y, a.z)], 1u);
  atomicAdd(&cnt[bucket_of(a.w, b.x, b.y)], 1u);
  atomicAdd(&cnt[bucket_of(b.z, b.w, c.x)], 1u);
  atomicAdd(&cnt[bucket_of(c.y, c.z, c.w)], 1u);
}

__global__ __launch_bounds__(256) void scan1_k(const unsigned* __restrict__ cnt,
                                               unsigned* __restrict__ scanA,
                                               unsigned* __restrict__ bsum) {
  __shared__ unsigned s[256];
  int t = (int)threadIdx.x, i = (int)blockIdx.x * 256 + t;
  unsigned v = cnt[i];
  s[t] = v;
  __syncthreads();
  for (int d = 1; d < 256; d <<= 1) {
    unsigned x = (t >= d) ? s[t - d] : 0u;
    __syncthreads();
    s[t] += x;
    __syncthreads();
  }
  scanA[i] = s[t] - v;  // exclusive within block
  if (t == 255) bsum[blockIdx.x] = s[255];
}

// 128 block sums (NBKT/256) scanned by one small block
__global__ __launch_bounds__(128) void scan2_k(unsigned* __restrict__ bsum) {
  __shared__ unsigned s[128];
  int t = (int)threadIdx.x;
  unsigned v = bsum[t];
  s[t] = v;
  __syncthreads();
  for (int d = 1; d < 128; d <<= 1) {
    unsigned x = (t >= d) ? s[t - d] : 0u;
    __syncthreads();
    s[t] += x;
    __syncthreads();
  }
  bsum[t] = s[t] - v;  // exclusive across blocks
}

__global__ __launch_bounds__(256) void scat_k(const float* __restrict__ coords,
                                              unsigned* __restrict__ scanA,
                                              const unsigned* __restrict__ bsum,
                                              f4* __restrict__ sorted) {
  int t = (int)blockIdx.x * 256 + (int)threadIdx.x;  // < NPTS/4
  const f4* C = (const f4*)(coords + (size_t)t * 12);
  f4 a = C[0], b = C[1], c = C[2];
  unsigned n0 = (unsigned)(t * 4);
  int b0 = bucket_of(a.x, a.y, a.z);
  unsigned s0 = atomicAdd(&scanA[b0], 1u) + bsum[b0 >> 8];
  f4 v0; v0.x = a.x; v0.y = a.y; v0.z = a.z; v0.w = __uint_as_float(n0);
  sorted[s0] = v0;
  int b1 = bucket_of(a.w, b.x, b.y);
  unsigned s1 = atomicAdd(&scanA[b1], 1u) + bsum[b1 >> 8];
  f4 v1; v1.x = a.w; v1.y = b.x; v1.z = b.y; v1.w = __uint_as_float(n0 + 1u);
  sorted[s1] = v1;
  int b2 = bucket_of(b.z, b.w, c.x);
  unsigned s2 = atomicAdd(&scanA[b2], 1u) + bsum[b2 >> 8];
  f4 v2; v2.x = b.z; v2.y = b.w; v2.z = c.x; v2.w = __uint_as_float(n0 + 2u);
  sorted[s2] = v2;
  int b3 = bucket_of(c.y, c.z, c.w);
  unsigned s3 = atomicAdd(&scanA[b3], 1u) + bsum[b3 >> 8];
  f4 v3; v3.x = c.y; v3.y = c.z; v3.z = c.w; v3.w = __uint_as_float(n0 + 3u);
  sorted[s3] = v3;
}

// ---- grid level, bf16 cell path (r8-validated) -----------------------------
struct GB {
  f4 l0, l1;
  float wx0, wx1, w00, w10, w01, w11;
};

template <int LVL>
__device__ __forceinline__ void gridb_issue(const Params& p,
                                            const char* __restrict__ ws,
                                            float cx, float cy, float cz,
                                            GB& s) {
  float rf = p.resf[LVL];
  int res = (int)rf;
  float sx = cx * rf, sy = cy * rf, sz = cz * rf;
  float bx = floorf(sx), by = floorf(sy), bz = floorf(sz);
  float fx = sx - bx, fy = sy - by, fz = sz - bz;
  int ix = (int)bx, iy = (int)by, iz = (int)bz;  // coords in [0,1): no clip
  int cell = (iz * res + iy) * res + ix;
  const f4* src = (const f4*)(ws + (size_t)p.cellOffB[LVL] + (size_t)cell * 32);
  s.l0 = src[0]; s.l1 = src[1];
  float wy0 = 1.f - fy, wy1 = fy, wz0 = 1.f - fz, wz1 = fz;
  s.wx0 = 1.f - fx; s.wx1 = fx;
  s.w00 = wy0 * wz0; s.w10 = wy1 * wz0; s.w01 = wy0 * wz1; s.w11 = wy1 * wz1;
}

__device__ __forceinline__ f2 gridb_consume(const GB& s) {
  float a0 = 0.f, a1 = 0.f;
  unsigned u;
  u = __float_as_uint(s.l0.x); a0 = fmaf(s.wx0 * s.w00, bflo(u), a0); a1 = fmaf(s.wx0 * s.w00, bfhi(u), a1);
  u = __float_as_uint(s.l0.y); a0 = fmaf(s.wx1 * s.w00, bflo(u), a0); a1 = fmaf(s.wx1 * s.w00, bfhi(u), a1);
  u = __float_as_uint(s.l0.z); a0 = fmaf(s.wx0 * s.w10, bflo(u), a0); a1 = fmaf(s.wx0 * s.w10, bfhi(u), a1);
  u = __float_as_uint(s.l0.w); a0 = fmaf(s.wx1 * s.w10, bflo(u), a0); a1 = fmaf(s.wx1 * s.w10, bfhi(u), a1);
  u = __float_as_uint(s.l1.x); a0 = fmaf(s.wx0 * s.w01, bflo(u), a0); a1 = fmaf(s.wx0 * s.w01, bfhi(u), a1);
  u = __float_as_uint(s.l1.y); a0 = fmaf(s.wx1 * s.w01, bflo(u), a0); a1 = fmaf(s.wx1 * s.w01, bfhi(u), a1);
  u = __float_as_uint(s.l1.z); a0 = fmaf(s.wx0 * s.w11, bflo(u), a0); a1 = fmaf(s.wx0 * s.w11, bfhi(u), a1);
  u = __float_as_uint(s.l1.w); a0 = fmaf(s.wx1 * s.w11, bflo(u), a0); a1 = fmaf(s.wx1 * s.w11, bfhi(u), a1);
  f2 r; r.x = a0; r.y = a1;
  return r;
}

// ---- grid level, direct f32 fallback (r7-validated) ------------------------
template <int LVL>
__device__ __forceinline__ f2 grid_direct(const Params& p,
                                          const f2* __restrict__ emb, float cx,
                                          float cy, float cz) {
  float rf = p.resf[LVL];
  int res = (int)rf;
  int s = res + 1, s2 = s * s;
  const f2* tab = emb + p.off[LVL];
  float sx = cx * rf, sy = cy * rf, sz = cz * rf;
  float bx = floorf(sx), by = floorf(sy), bz = floorf(sz);
  float fx = sx - bx, fy = sy - by, fz = sz - bz;
  int ix = (int)bx, iy = (int)by, iz = (int)bz;
  int bse = ix + iy * s + iz * s2;
  f2 e0 = tab[bse], e1 = tab[bse + 1];
  f2 e2 = tab[bse + s], e3 = tab[bse + s + 1];
  f2 e4 = tab[bse + s2], e5 = tab[bse + s2 + 1];
  f2 e6 = tab[bse + s2 + s], e7 = tab[bse + s2 + s + 1];
  float wx0 = 1.f - fx, wx1 = fx, wy0 = 1.f - fy, wy1 = fy;
  float wz0 = 1.f - fz, wz1 = fz;
  float w00 = wy0 * wz0, w10 = wy1 * wz0, w01 = wy0 * wz1, w11 = wy1 * wz1;
  float a0 = 0.f, a1 = 0.f;
  a0 = fmaf(wx0 * w00, e0.x, a0); a1 = fmaf(wx0 * w00, e0.y, a1);
  a0 = fmaf(wx1 * w00, e1.x, a0); a1 = fmaf(wx1 * w00, e1.y, a1);
  a0 = fmaf(wx0 * w10, e2.x, a0); a1 = fmaf(wx0 * w10, e2.y, a1);
  a0 = fmaf(wx1 * w10, e3.x, a0); a1 = fmaf(wx1 * w10, e3.y, a1);
  a0 = fmaf(wx0 * w01, e4.x, a0); a1 = fmaf(wx0 * w01, e4.y, a1);
  a0 = fmaf(wx1 * w01, e5.x, a0); a1 = fmaf(wx1 * w01, e5.y, a1);
  a0 = fmaf(wx0 * w11, e6.x, a0); a1 = fmaf(wx0 * w11, e6.y, a1);
  a0 = fmaf(wx1 * w11, e7.x, a0); a1 = fmaf(wx1 * w11, e7.y, a1);
  f2 r; r.x = a0; r.y = a1;
  return r;
}

// ---- hashed level, LEAN bf16 chunk path (r14-validated) --------------------
struct HB {
  f4 cA0, cA1, cA2, cA3;
  unsigned uB0, uB1, uB2, uB3;
  float wA0, wB0, wA1, wB1, wA2, wB2, wA3, wB3;
  int kA0, kA1, kA2, kA3, kB0, kB1, kB2, kB3;
  bool sameChunk;
};

template <int LVL>
__device__ __forceinline__ void hashb_issue(const Params& p,
                                            const char* __restrict__ ws,
                                            float cx, float cy, float cz,
                                            HB& s) {
  float rf = p.resf[LVL];
  const f4* tab = (const f4*)(ws + (size_t)p.hOffB[LVL - 7]);
  const unsigned* t32 = (const unsigned*)tab;
  float sx = cx * rf, sy = cy * rf, sz = cz * rf;
  float bx = floorf(sx), by = floorf(sy), bz = floorf(sz);
  float fx = sx - bx, fy = sy - by, fz = sz - bz;
  unsigned ix = (unsigned)(int)bx, iy = (unsigned)(int)by,
           iz = (unsigned)(int)bz;
  unsigned jx = ix + 1u;
  unsigned ty0 = iy * PI1, ty1 = ty0 + PI1;  // uint32 wraparound = numpy
  unsigned tz0 = iz * PI2, tz1 = tz0 + PI2;
  unsigned e00 = ty0 ^ tz0, e10 = ty1 ^ tz0, e01 = ty0 ^ tz1, e11 = ty1 ^ tz1;
  float wx0 = 1.f - fx, wx1 = fx, wy0 = 1.f - fy, wy1 = fy;
  float wz0 = 1.f - fz, wz1 = fz;
  float w00 = wy0 * wz0, w10 = wy1 * wz0, w01 = wy0 * wz1, w11 = wy1 * wz1;
  unsigned iA0 = (ix ^ e00) & TMASK, iB0 = (jx ^ e00) & TMASK;
  unsigned iA1 = (ix ^ e10) & TMASK, iB1 = (jx ^ e10) & TMASK;
  unsigned iA2 = (ix ^ e01) & TMASK, iB2 = (jx ^ e01) & TMASK;
  unsigned iA3 = (ix ^ e11) & TMASK, iB3 = (jx ^ e11) & TMASK;
  s.sameChunk = (ix & 3u) != 3u;
  s.uB0 = 0u; s.uB1 = 0u; s.uB2 = 0u; s.uB3 = 0u;
  if (!s.sameChunk) {  // 25% of lanes: masked dword loads
    s.uB0 = t32[iB0]; s.uB1 = t32[iB1];
    s.uB2 = t32[iB2]; s.uB3 = t32[iB3];
  }
  s.cA0 = tab[iA0 >> 2]; s.cA1 = tab[iA1 >> 2];
  s.cA2 = tab[iA2 >> 2]; s.cA3 = tab[iA3 >> 2];
  s.kA0 = (int)(iA0 & 3u); s.kA1 = (int)(iA1 & 3u);
  s.kA2 = (int)(iA2 & 3u); s.kA3 = (int)(iA3 & 3u);
  s.kB0 = (int)(iB0 & 3u); s.kB1 = (int)(iB1 & 3u);
  s.kB2 = (int)(iB2 & 3u); s.kB3 = (int)(iB3 & 3u);
  s.wA0 = wx0 * w00; s.wB0 = wx1 * w00;
  s.wA1 = wx0 * w10; s.wB1 = wx1 * w10;
  s.wA2 = wx0 * w01; s.wB2 = wx1 * w01;
  s.wA3 = wx0 * w11; s.wB3 = wx1 * w11;
}

__device__ __forceinline__ void hbpair(f4 cA, unsigned uBl, int kA, int kB,
                                       bool same, float wA, float wB,
                                       float& a0, float& a1) {
  unsigned uA = sel4(cA, kA);
  unsigned uB = same ? sel4(cA, kB) : uBl;
  a0 = fmaf(wA, bflo(uA), a0); a1 = fmaf(wA, bfhi(uA), a1);
  a0 = fmaf(wB, bflo(uB), a0); a1 = fmaf(wB, bfhi(uB), a1);
}

__device__ __forceinline__ f2 hashb_consume(const HB& s) {
  float a0 = 0.f, a1 = 0.f;
  hbpair(s.cA0, s.uB0, s.kA0, s.kB0, s.sameChunk, s.wA0, s.wB0, a0, a1);
  hbpair(s.cA1, s.uB1, s.kA1, s.kB1, s.sameChunk, s.wA1, s.wB1, a0, a1);
  hbpair(s.cA2, s.uB2, s.kA2, s.kB2, s.sameChunk, s.wA2, s.wB2, a0, a1);
  hbpair(s.cA3, s.uB3, s.kA3, s.kB3, s.sameChunk, s.wA3, s.wB3, a0, a1);
  f2 r; r.x = a0; r.y = a1;
  return r;
}

// ---- hashed level, direct f32 fallback (r7-validated) ----------------------
struct HS {
  f4 lo0, hi0, lo1, hi1, lo2, hi2, lo3, hi3;
  float wA0, wB0, wA1, wB1, wA2, wB2, wA3, wB3;
  int oA0, oB0, oA1, oB1, oA2, oB2, oA3, oB3;
};

template <int LVL>
__device__ __forceinline__ void hash_issue(const Params& p,
                                           const f2* __restrict__ emb,
                                           float cx, float cy, float cz,
                                           HS& s) {
  float rf = p.resf[LVL];
  const f2* tab = emb + p.off[LVL];
  float sx = cx * rf, sy = cy * rf, sz = cz * rf;
  float bx = floorf(sx), by = floorf(sy), bz = floorf(sz);
  float fx = sx - bx, fy = sy - by, fz = sz - bz;
  unsigned ix = (unsigned)(int)bx, iy = (unsigned)(int)by,
           iz = (unsigned)(int)bz;
  unsigned jx = ix + 1u;
  unsigned ty0 = iy * PI1, ty1 = ty0 + PI1;
  unsigned tz0 = iz * PI2, tz1 = tz0 + PI2;
  unsigned e00 = ty0 ^ tz0, e10 = ty1 ^ tz0, e01 = ty0 ^ tz1, e11 = ty1 ^ tz1;
  float wx0 = 1.f - fx, wx1 = fx, wy0 = 1.f - fy, wy1 = fy;
  float wz0 = 1.f - fz, wz1 = fz;
  float w00 = wy0 * wz0, w10 = wy1 * wz0, w01 = wy0 * wz1, w11 = wy1 * wz1;
  unsigned iA, iB;
  iA = (ix ^ e00) & TMASK; iB = (jx ^ e00) & TMASK;
  s.oA0 = (int)(iA & 1u); s.oB0 = (int)(iB & 1u);
  s.lo0 = *(const f4*)(tab + (iA & ~1u)); s.hi0 = *(const f4*)(tab + (iB & ~1u));
  s.wA0 = wx0 * w00; s.wB0 = wx1 * w00;
  iA = (ix ^ e10) & TMASK; iB = (jx ^ e10) & TMASK;
  s.oA1 = (int)(iA & 1u); s.oB1 = (int)(iB & 1u);
  s.lo1 = *(const f4*)(tab + (iA & ~1u)); s.hi1 = *(const f4*)(tab + (iB & ~1u));
  s.wA1 = wx0 * w10; s.wB1 = wx1 * w10;
  iA = (ix ^ e01) & TMASK; iB = (jx ^ e01) & TMASK;
  s.oA2 = (int)(iA & 1u); s.oB2 = (int)(iB & 1u);
  s.lo2 = *(const f4*)(tab + (iA & ~1u)); s.hi2 = *(const f4*)(tab + (iB & ~1u));
  s.wA2 = wx0 * w01; s.wB2 = wx1 * w01;
  iA = (ix ^ e11) & TMASK; iB = (jx ^ e11) & TMASK;
  s.oA3 = (int)(iA & 1u); s.oB3 = (int)(iB & 1u);
  s.lo3 = *(const f4*)(tab + (iA & ~1u)); s.hi3 = *(const f4*)(tab + (iB & ~1u));
  s.wA3 = wx0 * w11; s.wB3 = wx1 * w11;
}

__device__ __forceinline__ void hpair2(f4 lo, f4 hi, int oA, int oB, float wA,
                                       float wB, float& a0, float& a1) {
  float eAx = oA ? lo.z : lo.x, eAy = oA ? lo.w : lo.y;
  float eBx = oB ? hi.z : hi.x, eBy = oB ? hi.w : hi.y;
  a0 = fmaf(wA, eAx, a0); a1 = fmaf(wA, eAy, a1);
  a0 = fmaf(wB, eBx, a0); a1 = fmaf(wB, eBy, a1);
}

__device__ __forceinline__ f2 hash_consume(const HS& s) {
  float a0 = 0.f, a1 = 0.f;
  hpair2(s.lo0, s.hi0, s.oA0, s.oB0, s.wA0, s.wB0, a0, a1);
  hpair2(s.lo1, s.hi1, s.oA1, s.oB1, s.wA1, s.wB1, a0, a1);
  hpair2(s.lo2, s.hi2, s.oA2, s.oB2, s.wA2, s.wB2, a0, a1);
  hpair2(s.lo3, s.hi3, s.oA3, s.oB3, s.wA3, s.wB3, a0, a1);
  f2 r; r.x = a0; r.y = a1;
  return r;
}

// ---- main henc: r14-identical (1 pt/thread, VGPR 32, 83% occupancy) --------
template <int LVL, int MODE>
__device__ __forceinline__ void do_phase(const Params& p,
                                         const f2* __restrict__ emb,
                                         const char* __restrict__ ws, float cx,
                                         float cy, float cz, int pt,
                                         unsigned* lds) {
  f2 r;
  if constexpr (LVL < NGRID) {
    if constexpr (MODE < 2) {
      GB s;
      gridb_issue<LVL>(p, ws, cx, cy, cz, s);
      r = gridb_consume(s);
    } else {
      r = grid_direct<LVL>(p, emb, cx, cy, cz);
    }
  } else {
    if constexpr (MODE == 0) {
      HB s;
      hashb_issue<LVL>(p, ws, cx, cy, cz, s);
      r = hashb_consume(s);
    } else {
      HS s;
      hash_issue<LVL>(p, emb, cx, cy, cz, s);
      r = hash_consume(s);
    }
  }
  lds[pt * 8 + ((LVL & 7) ^ swz(pt))] = packbf(r);
}

template <bool SORTED>
__device__ __forceinline__ void readout(float* __restrict__ out,
                                        const unsigned* lds,
                                        const unsigned* oiLds, int n0, int h,
                                        int tid) {
#pragma unroll
  for (int j = 0; j < 4; ++j) {
    int f = tid + BLK * j;  // f4 index 0..2047
    int pt = f >> 2, k = f & 3;
    int s = swz(pt);
    unsigned u0 = lds[pt * 8 + ((2 * k) ^ s)];
    unsigned u1 = lds[pt * 8 + ((2 * k + 1) ^ s)];
    f4 o4; o4.x = bflo(u0); o4.y = bfhi(u0); o4.z = bflo(u1); o4.w = bfhi(u1);
    size_t base = SORTED ? (size_t)oiLds[pt] * 32 : (size_t)(n0 + pt) * 32;
    __builtin_nontemporal_store(o4, (f4*)(out + base + h * 16 + k * 4));
  }
}

template <int MODE, bool SORTED>
__global__ __launch_bounds__(BLK, 4) void henc(const float* __restrict__ coords,
                                               const f2* __restrict__ emb,
                                               float* __restrict__ out,
                                               const char* __restrict__ ws,
                                               const f4* __restrict__ sorted,
                                               Params p) {
  __shared__ unsigned lds[PTS_PER_BLK * 8];  // 16 KB packed bf16
  __shared__ unsigned oiLds[PTS_PER_BLK];    // 2 KB original indices
  const int tid = (int)threadIdx.x;
  const int n0 = (int)blockIdx.x * PTS_PER_BLK;
  const int pt = tid;

  float cx, cy, cz;
  if constexpr (SORTED) {
    f4 s0 = sorted[n0 + pt];  // perfectly coalesced f4 per lane
    cx = s0.x; cy = s0.y; cz = s0.z;
    oiLds[pt] = __float_as_uint(s0.w);
  } else {
    cx = coords[3 * (n0 + pt) + 0];
    cy = coords[3 * (n0 + pt) + 1];
    cz = coords[3 * (n0 + pt) + 2];
  }

  do_phase<0, MODE>(p, emb, ws, cx, cy, cz, pt, lds);
  do_phase<1, MODE>(p, emb, ws, cx, cy, cz, pt, lds);
  do_phase<2, MODE>(p, emb, ws, cx, cy, cz, pt, lds);
  do_phase<3, MODE>(p, emb, ws, cx, cy, cz, pt, lds);
  do_phase<4, MODE>(p, emb, ws, cx, cy, cz, pt, lds);
  do_phase<5, MODE>(p, emb, ws, cx, cy, cz, pt, lds);
  do_phase<6, MODE>(p, emb, ws, cx, cy, cz, pt, lds);
  do_phase<7, MODE>(p, emb, ws, cx, cy, cz, pt, lds);
  __syncthreads();
  readout<SORTED>(out, lds, oiLds, n0, 0, tid);
  __syncthreads();  // LDS reuse fence

  do_phase<8, MODE>(p, emb, ws, cx, cy, cz, pt, lds);
  do_phase<9, MODE>(p, emb, ws, cx, cy, cz, pt, lds);
  do_phase<10, MODE>(p, emb, ws, cx, cy, cz, pt, lds);
  do_phase<11, MODE>(p, emb, ws, cx, cy, cz, pt, lds);
  do_phase<12, MODE>(p, emb, ws, cx, cy, cz, pt, lds);
  do_phase<13, MODE>(p, emb, ws, cx, cy, cz, pt, lds);
  do_phase<14, MODE>(p, emb, ws, cx, cy, cz, pt, lds);
  do_phase<15, MODE>(p, emb, ws, cx, cy, cz, pt, lds);
  __syncthreads();
  readout<SORTED>(out, lds, oiLds, n0, 1, tid);
}

extern "C" void kernel_launch(void* const* d_in, const int* in_sizes, int n_in,
                              void* d_out, int out_size, void* d_ws,
                              size_t ws_size, hipStream_t stream) {
  const float* coords = (const float*)d_in[0];
  const f2* emb = (const f2*)d_in[1];
  float* out = (float*)d_out;
  char* ws = (char*)d_ws;

  // Replicate Python's level_params() bit-exactly with host libm doubles.
  Params p;
  double b = pow(32.0, 1.0 / 15.0);
  long long cum = 0, cellCum = 0;
  int resMax = 64;
  for (int i = 0; i < NLVL; ++i) {
    int r = (int)floor(16.0 * pow(b, (double)i));
    p.resf[i] = (float)r;
    p.off[i] = (int)cum;
    long long e3 = (long long)(r + 1) * (r + 1) * (r + 1);
    cum += e3 > 524288 ? 524288 : e3;
    if (i < NGRID) {
      p.cellOffB[i] = (int)(cellCum * 32);  // bf16 cell = 32 B
      cellCum += (long long)r * r * r;
      if (i == NGRID - 1) resMax = r;
    }
  }
  long long gridB = ((cellCum * 32 + 63) / 64) * 64;
  for (int h = 0; h < NHASH; ++h)
    p.hOffB[h] = (int)(gridB + (long long)h * (524288 * 4));
  size_t needB = (size_t)gridB;                       // grid-only tier
  size_t needA = (size_t)(gridB + 9LL * 524288 * 4);  // full bf16 tier

  // sort-tier layout (after tables, 256-aligned)
  size_t cntOff = (needA + 255) & ~(size_t)255;
  size_t exclOff = cntOff + (size_t)NBKT * 4;
  size_t bsumOff = exclOff + (size_t)NBKT * 4;
  size_t sortedOff = (bsumOff + 4096 + 255) & ~(size_t)255;
  size_t needS = sortedOff + (size_t)NPTS * 16;  // ~67 MB

  int mode = ws_size >= needA ? 0 : (ws_size >= needB ? 1 : 2);
  bool doSort = ws_size >= needS;
  p.cnt = (unsigned*)(ws + cntOff);

  if (mode == 0) {
    // y=16 slice zeroes the sort counters (replaces the memset node)
    int ny = doSort ? NLVL + 1 : NLVL;
    repack_all<<<dim3(524288 / 256, ny), dim3(256), 0, stream>>>(emb, ws, p);
    if (doSort) {
      unsigned* cnt = (unsigned*)(ws + cntOff);
      unsigned* excl = (unsigned*)(ws + exclOff);
      unsigned* bsum = (unsigned*)(ws + bsumOff);
      f4* sorted = (f4*)(ws + sortedOff);
      hist_k<<<dim3(NPTS / 4 / 256), dim3(256), 0, stream>>>(coords, cnt);
      scan1_k<<<dim3(NBKT / 256), dim3(256), 0, stream>>>(cnt, excl, bsum);
      scan2_k<<<dim3(1), dim3(128), 0, stream>>>(bsum);
      scat_k<<<dim3(NPTS / 4 / 256), dim3(256), 0, stream>>>(coords, excl,
                                                             bsum, sorted);
      henc<0, true><<<dim3(NBLK), dim3(BLK), 0, stream>>>(coords, emb, out, ws,
                                                          sorted, p);
    } else {
      henc<0, false><<<dim3(NBLK), dim3(BLK), 0, stream>>>(coords, emb, out,
                                                           ws, nullptr, p);
    }
  } else if (mode == 1) {
    int bx = (resMax * resMax * resMax + 255) / 256;
    repack_grid<<<dim3(bx, NGRID), dim3(256), 0, stream>>>(emb, ws, p);
    henc<1, false><<<dim3(NBLK), dim3(BLK), 0, stream>>>(coords, emb, out, ws,
                                                         nullptr, p);
  } else {
    henc<2, false><<<dim3(NBLK), dim3(BLK), 0, stream>>>(coords, emb, out, ws,
                                                         nullptr, p);
  }
}

// Round 18
// 463.479 us; speedup vs baseline: 1.0788x; 1.0788x over previous
//
#include <hip/hip_runtime.h>
#include <math.h>

namespace {
constexpr int NPTS = 1 << 21;
constexpr int NLVL = 16;
constexpr unsigned TMASK = 0x7FFFFu;  // all hashed levels have size T = 2^19
constexpr unsigned PI1 = 2654435761u;
constexpr unsigned PI2 = 805459861u;
constexpr int BLK = 512;
constexpr int PTS_PER_BLK = 512;          // 1 pt/thread (r14-validated)
constexpr int NBLK = NPTS / PTS_PER_BLK;  // 4096
constexpr int NGRID = 7;                  // levels 0..6 grid-indexed
constexpr int NHASH = 9;                  // levels 7..15 hashed, size 2^19
constexpr int BRES = 64;                  // sort bucket grid (r16-validated;
                                          // r17's 32 regressed henc locality)
constexpr int NBKT = BRES * BRES * BRES;  // 262144

typedef float f2 __attribute__((ext_vector_type(2)));
typedef float f4 __attribute__((ext_vector_type(4)));
typedef unsigned u4 __attribute__((ext_vector_type(4)));

struct Params {
  float resf[NLVL];
  int off[NLVL];        // entry offsets into emb (f2 units)
  int cellOffB[NGRID];  // byte offsets of bf16 cell tables in ws
  int hOffB[NHASH];     // byte offsets of bf16 hashed tables in ws
  unsigned* cnt;        // bucket counters (zeroed by repack_all slice 16)
};

__device__ __forceinline__ int swz(int pt) { return (pt ^ (pt >> 3)) & 7; }

__device__ __forceinline__ unsigned bfrne(float x) {  // f32 -> bf16 bits, RNE
  unsigned f = __float_as_uint(x);
  return (f + 0x7FFFu + ((f >> 16) & 1u)) >> 16;
}
__device__ __forceinline__ unsigned packbf(f2 e) {
  return bfrne(e.x) | (bfrne(e.y) << 16);
}
__device__ __forceinline__ float bflo(unsigned u) {
  return __uint_as_float(u << 16);
}
__device__ __forceinline__ float bfhi(unsigned u) {
  return __uint_as_float(u & 0xFFFF0000u);
}
__device__ __forceinline__ unsigned sel4(f4 v, int k) {
  float g = (k & 2) ? ((k & 1) ? v.w : v.z) : ((k & 1) ? v.y : v.x);
  return __float_as_uint(g);
}
__device__ __forceinline__ int bucket_of(float cx, float cy, float cz) {
  return (int)(cx * 64.f) + ((int)(cy * 64.f) << 6) + ((int)(cz * 64.f) << 12);
}
}  // namespace

// ---- fused repack (r14-validated) + counter zeroing ------------------------
// y=0..6: grid cell-major bf16 (32 B/cell). y=7..15: hashed flat bf16 copy.
// y=16: zero the 256K sort counters (runs strictly before hist_k by stream
// order).
__global__ __launch_bounds__(256) void repack_all(const f2* __restrict__ emb,
                                                  char* __restrict__ ws,
                                                  Params p) {
  int y = (int)blockIdx.y;
  int t = (int)blockIdx.x * 256 + (int)threadIdx.x;  // < 524288
  if (y == NLVL) {  // counter zero slice
    if (t < NBKT) p.cnt[t] = 0u;
    return;
  }
  if (y >= NGRID) {
    int h = y - NGRID;  // static-index chain (rule #20)
    int off = p.off[7], hob = p.hOffB[0];
    if (h == 1) { off = p.off[8]; hob = p.hOffB[1]; }
    if (h == 2) { off = p.off[9]; hob = p.hOffB[2]; }
    if (h == 3) { off = p.off[10]; hob = p.hOffB[3]; }
    if (h == 4) { off = p.off[11]; hob = p.hOffB[4]; }
    if (h == 5) { off = p.off[12]; hob = p.hOffB[5]; }
    if (h == 6) { off = p.off[13]; hob = p.hOffB[6]; }
    if (h == 7) { off = p.off[14]; hob = p.hOffB[7]; }
    if (h == 8) { off = p.off[15]; hob = p.hOffB[8]; }
    ((unsigned*)(ws + (size_t)hob))[t] = packbf(emb[off + t]);
    return;
  }
  float rf = p.resf[0];  // static-index chain
  int off = p.off[0], cob = p.cellOffB[0];
  if (y == 1) { rf = p.resf[1]; off = p.off[1]; cob = p.cellOffB[1]; }
  if (y == 2) { rf = p.resf[2]; off = p.off[2]; cob = p.cellOffB[2]; }
  if (y == 3) { rf = p.resf[3]; off = p.off[3]; cob = p.cellOffB[3]; }
  if (y == 4) { rf = p.resf[4]; off = p.off[4]; cob = p.cellOffB[4]; }
  if (y == 5) { rf = p.resf[5]; off = p.off[5]; cob = p.cellOffB[5]; }
  if (y == 6) { rf = p.resf[6]; off = p.off[6]; cob = p.cellOffB[6]; }
  int res = (int)rf;
  if (t >= res * res * res) return;
  int x = t % res, q = t / res, yy = q % res, z = q / res;
  int s = res + 1, s2 = s * s;
  const f2* base = emb + off + (x + yy * s + z * s2);
  u4 d0, d1;  // corner order j = dx + 2*dy + 4*dz (validated r3-r16)
  d0.x = packbf(base[0]);       d0.y = packbf(base[1]);
  d0.z = packbf(base[s]);       d0.w = packbf(base[s + 1]);
  d1.x = packbf(base[s2]);      d1.y = packbf(base[s2 + 1]);
  d1.z = packbf(base[s2 + s]);  d1.w = packbf(base[s2 + s + 1]);
  u4* dst = (u4*)(ws + (size_t)cob + (size_t)t * 32);
  dst[0] = d0; dst[1] = d1;
}

// ---- legacy grid repack (mode-1 fallback tier only) ------------------------
__global__ __launch_bounds__(256) void repack_grid(const f2* __restrict__ emb,
                                                   char* __restrict__ ws,
                                                   Params p) {
  int lvl = (int)blockIdx.y;
  float rf = p.resf[0];
  int off = p.off[0], cob = p.cellOffB[0];
  if (lvl == 1) { rf = p.resf[1]; off = p.off[1]; cob = p.cellOffB[1]; }
  if (lvl == 2) { rf = p.resf[2]; off = p.off[2]; cob = p.cellOffB[2]; }
  if (lvl == 3) { rf = p.resf[3]; off = p.off[3]; cob = p.cellOffB[3]; }
  if (lvl == 4) { rf = p.resf[4]; off = p.off[4]; cob = p.cellOffB[4]; }
  if (lvl == 5) { rf = p.resf[5]; off = p.off[5]; cob = p.cellOffB[5]; }
  if (lvl == 6) { rf = p.resf[6]; off = p.off[6]; cob = p.cellOffB[6]; }
  int res = (int)rf;
  int t = (int)blockIdx.x * 256 + (int)threadIdx.x;
  if (t >= res * res * res) return;
  int x = t % res, q = t / res, y = q % res, z = q / res;
  int s = res + 1, s2 = s * s;
  const f2* base = emb + off + (x + y * s + z * s2);
  u4 d0, d1;
  d0.x = packbf(base[0]);       d0.y = packbf(base[1]);
  d0.z = packbf(base[s]);       d0.w = packbf(base[s + 1]);
  d1.x = packbf(base[s2]);      d1.y = packbf(base[s2 + 1]);
  d1.z = packbf(base[s2 + s]);  d1.w = packbf(base[s2 + s + 1]);
  u4* dst = (u4*)(ws + (size_t)cob + (size_t)t * 32);
  dst[0] = d0; dst[1] = d1;
}

// ---- bucket-sort pipeline (r13/r14-validated; order-independent values) ----
__global__ __launch_bounds__(256) void hist_k(const float* __restrict__ coords,
                                              unsigned* __restrict__ cnt) {
  int t = (int)blockIdx.x * 256 + (int)threadIdx.x;  // < NPTS/4
  const f4* C = (const f4*)(coords + (size_t)t * 12);
  f4 a = C[0], b = C[1], c = C[2];
  atomicAdd(&cnt[bucket_of(a.x, a.y, a.z)], 1u);
  atomicAdd(&cnt[bucket_of(a.w, b.x, b.y)], 1u);
  atomicAdd(&cnt[bucket_of(b.z, b.w, c.x)], 1u);
  atomicAdd(&cnt[bucket_of(c.y, c.z, c.w)], 1u);
}

__global__ __launch_bounds__(256) void scan1_k(const unsigned* __restrict__ cnt,
                                               unsigned* __restrict__ scanA,
                                               unsigned* __restrict__ bsum) {
  __shared__ unsigned s[256];
  int t = (int)threadIdx.x, i = (int)blockIdx.x * 256 + t;
  unsigned v = cnt[i];
  s[t] = v;
  __syncthreads();
  for (int d = 1; d < 256; d <<= 1) {
    unsigned x = (t >= d) ? s[t - d] : 0u;
    __syncthreads();
    s[t] += x;
    __syncthreads();
  }
  scanA[i] = s[t] - v;  // exclusive within block
  if (t == 255) bsum[blockIdx.x] = s[255];
}

__global__ __launch_bounds__(1024) void scan2_k(unsigned* __restrict__ bsum) {
  __shared__ unsigned s[1024];
  int t = (int)threadIdx.x;
  unsigned v = bsum[t];
  s[t] = v;
  __syncthreads();
  for (int d = 1; d < 1024; d <<= 1) {
    unsigned x = (t >= d) ? s[t - d] : 0u;
    __syncthreads();
    s[t] += x;
    __syncthreads();
  }
  bsum[t] = s[t] - v;  // exclusive across blocks
}

__global__ __launch_bounds__(256) void scat_k(const float* __restrict__ coords,
                                              unsigned* __restrict__ scanA,
                                              const unsigned* __restrict__ bsum,
                                              f4* __restrict__ sorted) {
  int t = (int)blockIdx.x * 256 + (int)threadIdx.x;  // < NPTS/4
  const f4* C = (const f4*)(coords + (size_t)t * 12);
  f4 a = C[0], b = C[1], c = C[2];
  unsigned n0 = (unsigned)(t * 4);
  int b0 = bucket_of(a.x, a.y, a.z);
  unsigned s0 = atomicAdd(&scanA[b0], 1u) + bsum[b0 >> 8];
  f4 v0; v0.x = a.x; v0.y = a.y; v0.z = a.z; v0.w = __uint_as_float(n0);
  sorted[s0] = v0;
  int b1 = bucket_of(a.w, b.x, b.y);
  unsigned s1 = atomicAdd(&scanA[b1], 1u) + bsum[b1 >> 8];
  f4 v1; v1.x = a.w; v1.y = b.x; v1.z = b.y; v1.w = __uint_as_float(n0 + 1u);
  sorted[s1] = v1;
  int b2 = bucket_of(b.z, b.w, c.x);
  unsigned s2 = atomicAdd(&scanA[b2], 1u) + bsum[b2 >> 8];
  f4 v2; v2.x = b.z; v2.y = b.w; v2.z = c.x; v2.w = __uint_as_float(n0 + 2u);
  sorted[s2] = v2;
  int b3 = bucket_of(c.y, c.z, c.w);
  unsigned s3 = atomicAdd(&scanA[b3], 1u) + bsum[b3 >> 8];
  f4 v3; v3.x = c.y; v3.y = c.z; v3.z = c.w; v3.w = __uint_as_float(n0 + 3u);
  sorted[s3] = v3;
}

// ---- grid level, bf16 cell path (r8-validated) -----------------------------
struct GB {
  f4 l0, l1;
  float wx0, wx1, w00, w10, w01, w11;
};

template <int LVL>
__device__ __forceinline__ void gridb_issue(const Params& p,
                                            const char* __restrict__ ws,
                                            float cx, float cy, float cz,
                                            GB& s) {
  float rf = p.resf[LVL];
  int res = (int)rf;
  float sx = cx * rf, sy = cy * rf, sz = cz * rf;
  float bx = floorf(sx), by = floorf(sy), bz = floorf(sz);
  float fx = sx - bx, fy = sy - by, fz = sz - bz;
  int ix = (int)bx, iy = (int)by, iz = (int)bz;  // coords in [0,1): no clip
  int cell = (iz * res + iy) * res + ix;
  const f4* src = (const f4*)(ws + (size_t)p.cellOffB[LVL] + (size_t)cell * 32);
  s.l0 = src[0]; s.l1 = src[1];
  float wy0 = 1.f - fy, wy1 = fy, wz0 = 1.f - fz, wz1 = fz;
  s.wx0 = 1.f - fx; s.wx1 = fx;
  s.w00 = wy0 * wz0; s.w10 = wy1 * wz0; s.w01 = wy0 * wz1; s.w11 = wy1 * wz1;
}

__device__ __forceinline__ f2 gridb_consume(const GB& s) {
  float a0 = 0.f, a1 = 0.f;
  unsigned u;
  u = __float_as_uint(s.l0.x); a0 = fmaf(s.wx0 * s.w00, bflo(u), a0); a1 = fmaf(s.wx0 * s.w00, bfhi(u), a1);
  u = __float_as_uint(s.l0.y); a0 = fmaf(s.wx1 * s.w00, bflo(u), a0); a1 = fmaf(s.wx1 * s.w00, bfhi(u), a1);
  u = __float_as_uint(s.l0.z); a0 = fmaf(s.wx0 * s.w10, bflo(u), a0); a1 = fmaf(s.wx0 * s.w10, bfhi(u), a1);
  u = __float_as_uint(s.l0.w); a0 = fmaf(s.wx1 * s.w10, bflo(u), a0); a1 = fmaf(s.wx1 * s.w10, bfhi(u), a1);
  u = __float_as_uint(s.l1.x); a0 = fmaf(s.wx0 * s.w01, bflo(u), a0); a1 = fmaf(s.wx0 * s.w01, bfhi(u), a1);
  u = __float_as_uint(s.l1.y); a0 = fmaf(s.wx1 * s.w01, bflo(u), a0); a1 = fmaf(s.wx1 * s.w01, bfhi(u), a1);
  u = __float_as_uint(s.l1.z); a0 = fmaf(s.wx0 * s.w11, bflo(u), a0); a1 = fmaf(s.wx0 * s.w11, bfhi(u), a1);
  u = __float_as_uint(s.l1.w); a0 = fmaf(s.wx1 * s.w11, bflo(u), a0); a1 = fmaf(s.wx1 * s.w11, bfhi(u), a1);
  f2 r; r.x = a0; r.y = a1;
  return r;
}

// ---- grid level, direct f32 fallback (r7-validated) ------------------------
template <int LVL>
__device__ __forceinline__ f2 grid_direct(const Params& p,
                                          const f2* __restrict__ emb, float cx,
                                          float cy, float cz) {
  float rf = p.resf[LVL];
  int res = (int)rf;
  int s = res + 1, s2 = s * s;
  const f2* tab = emb + p.off[LVL];
  float sx = cx * rf, sy = cy * rf, sz = cz * rf;
  float bx = floorf(sx), by = floorf(sy), bz = floorf(sz);
  float fx = sx - bx, fy = sy - by, fz = sz - bz;
  int ix = (int)bx, iy = (int)by, iz = (int)bz;
  int bse = ix + iy * s + iz * s2;
  f2 e0 = tab[bse], e1 = tab[bse + 1];
  f2 e2 = tab[bse + s], e3 = tab[bse + s + 1];
  f2 e4 = tab[bse + s2], e5 = tab[bse + s2 + 1];
  f2 e6 = tab[bse + s2 + s], e7 = tab[bse + s2 + s + 1];
  float wx0 = 1.f - fx, wx1 = fx, wy0 = 1.f - fy, wy1 = fy;
  float wz0 = 1.f - fz, wz1 = fz;
  float w00 = wy0 * wz0, w10 = wy1 * wz0, w01 = wy0 * wz1, w11 = wy1 * wz1;
  float a0 = 0.f, a1 = 0.f;
  a0 = fmaf(wx0 * w00, e0.x, a0); a1 = fmaf(wx0 * w00, e0.y, a1);
  a0 = fmaf(wx1 * w00, e1.x, a0); a1 = fmaf(wx1 * w00, e1.y, a1);
  a0 = fmaf(wx0 * w10, e2.x, a0); a1 = fmaf(wx0 * w10, e2.y, a1);
  a0 = fmaf(wx1 * w10, e3.x, a0); a1 = fmaf(wx1 * w10, e3.y, a1);
  a0 = fmaf(wx0 * w01, e4.x, a0); a1 = fmaf(wx0 * w01, e4.y, a1);
  a0 = fmaf(wx1 * w01, e5.x, a0); a1 = fmaf(wx1 * w01, e5.y, a1);
  a0 = fmaf(wx0 * w11, e6.x, a0); a1 = fmaf(wx0 * w11, e6.y, a1);
  a0 = fmaf(wx1 * w11, e7.x, a0); a1 = fmaf(wx1 * w11, e7.y, a1);
  f2 r; r.x = a0; r.y = a1;
  return r;
}

// ---- hashed level, LEAN bf16 chunk path (r14-validated) --------------------
struct HB {
  f4 cA0, cA1, cA2, cA3;
  unsigned uB0, uB1, uB2, uB3;
  float wA0, wB0, wA1, wB1, wA2, wB2, wA3, wB3;
  int kA0, kA1, kA2, kA3, kB0, kB1, kB2, kB3;
  bool sameChunk;
};

template <int LVL>
__device__ __forceinline__ void hashb_issue(const Params& p,
                                            const char* __restrict__ ws,
                                            float cx, float cy, float cz,
                                            HB& s) {
  float rf = p.resf[LVL];
  const f4* tab = (const f4*)(ws + (size_t)p.hOffB[LVL - 7]);
  const unsigned* t32 = (const unsigned*)tab;
  float sx = cx * rf, sy = cy * rf, sz = cz * rf;
  float bx = floorf(sx), by = floorf(sy), bz = floorf(sz);
  float fx = sx - bx, fy = sy - by, fz = sz - bz;
  unsigned ix = (unsigned)(int)bx, iy = (unsigned)(int)by,
           iz = (unsigned)(int)bz;
  unsigned jx = ix + 1u;
  unsigned ty0 = iy * PI1, ty1 = ty0 + PI1;  // uint32 wraparound = numpy
  unsigned tz0 = iz * PI2, tz1 = tz0 + PI2;
  unsigned e00 = ty0 ^ tz0, e10 = ty1 ^ tz0, e01 = ty0 ^ tz1, e11 = ty1 ^ tz1;
  float wx0 = 1.f - fx, wx1 = fx, wy0 = 1.f - fy, wy1 = fy;
  float wz0 = 1.f - fz, wz1 = fz;
  float w00 = wy0 * wz0, w10 = wy1 * wz0, w01 = wy0 * wz1, w11 = wy1 * wz1;
  unsigned iA0 = (ix ^ e00) & TMASK, iB0 = (jx ^ e00) & TMASK;
  unsigned iA1 = (ix ^ e10) & TMASK, iB1 = (jx ^ e10) & TMASK;
  unsigned iA2 = (ix ^ e01) & TMASK, iB2 = (jx ^ e01) & TMASK;
  unsigned iA3 = (ix ^ e11) & TMASK, iB3 = (jx ^ e11) & TMASK;
  s.sameChunk = (ix & 3u) != 3u;
  s.uB0 = 0u; s.uB1 = 0u; s.uB2 = 0u; s.uB3 = 0u;
  if (!s.sameChunk) {  // 25% of lanes: masked dword loads
    s.uB0 = t32[iB0]; s.uB1 = t32[iB1];
    s.uB2 = t32[iB2]; s.uB3 = t32[iB3];
  }
  s.cA0 = tab[iA0 >> 2]; s.cA1 = tab[iA1 >> 2];
  s.cA2 = tab[iA2 >> 2]; s.cA3 = tab[iA3 >> 2];
  s.kA0 = (int)(iA0 & 3u); s.kA1 = (int)(iA1 & 3u);
  s.kA2 = (int)(iA2 & 3u); s.kA3 = (int)(iA3 & 3u);
  s.kB0 = (int)(iB0 & 3u); s.kB1 = (int)(iB1 & 3u);
  s.kB2 = (int)(iB2 & 3u); s.kB3 = (int)(iB3 & 3u);
  s.wA0 = wx0 * w00; s.wB0 = wx1 * w00;
  s.wA1 = wx0 * w10; s.wB1 = wx1 * w10;
  s.wA2 = wx0 * w01; s.wB2 = wx1 * w01;
  s.wA3 = wx0 * w11; s.wB3 = wx1 * w11;
}

__device__ __forceinline__ void hbpair(f4 cA, unsigned uBl, int kA, int kB,
                                       bool same, float wA, float wB,
                                       float& a0, float& a1) {
  unsigned uA = sel4(cA, kA);
  unsigned uB = same ? sel4(cA, kB) : uBl;
  a0 = fmaf(wA, bflo(uA), a0); a1 = fmaf(wA, bfhi(uA), a1);
  a0 = fmaf(wB, bflo(uB), a0); a1 = fmaf(wB, bfhi(uB), a1);
}

__device__ __forceinline__ f2 hashb_consume(const HB& s) {
  float a0 = 0.f, a1 = 0.f;
  hbpair(s.cA0, s.uB0, s.kA0, s.kB0, s.sameChunk, s.wA0, s.wB0, a0, a1);
  hbpair(s.cA1, s.uB1, s.kA1, s.kB1, s.sameChunk, s.wA1, s.wB1, a0, a1);
  hbpair(s.cA2, s.uB2, s.kA2, s.kB2, s.sameChunk, s.wA2, s.wB2, a0, a1);
  hbpair(s.cA3, s.uB3, s.kA3, s.kB3, s.sameChunk, s.wA3, s.wB3, a0, a1);
  f2 r; r.x = a0; r.y = a1;
  return r;
}

// ---- hashed level, direct f32 fallback (r7-validated) ----------------------
struct HS {
  f4 lo0, hi0, lo1, hi1, lo2, hi2, lo3, hi3;
  float wA0, wB0, wA1, wB1, wA2, wB2, wA3, wB3;
  int oA0, oB0, oA1, oB1, oA2, oB2, oA3, oB3;
};

template <int LVL>
__device__ __forceinline__ void hash_issue(const Params& p,
                                           const f2* __restrict__ emb,
                                           float cx, float cy, float cz,
                                           HS& s) {
  float rf = p.resf[LVL];
  const f2* tab = emb + p.off[LVL];
  float sx = cx * rf, sy = cy * rf, sz = cz * rf;
  float bx = floorf(sx), by = floorf(sy), bz = floorf(sz);
  float fx = sx - bx, fy = sy - by, fz = sz - bz;
  unsigned ix = (unsigned)(int)bx, iy = (unsigned)(int)by,
           iz = (unsigned)(int)bz;
  unsigned jx = ix + 1u;
  unsigned ty0 = iy * PI1, ty1 = ty0 + PI1;
  unsigned tz0 = iz * PI2, tz1 = tz0 + PI2;
  unsigned e00 = ty0 ^ tz0, e10 = ty1 ^ tz0, e01 = ty0 ^ tz1, e11 = ty1 ^ tz1;
  float wx0 = 1.f - fx, wx1 = fx, wy0 = 1.f - fy, wy1 = fy;
  float wz0 = 1.f - fz, wz1 = fz;
  float w00 = wy0 * wz0, w10 = wy1 * wz0, w01 = wy0 * wz1, w11 = wy1 * wz1;
  unsigned iA, iB;
  iA = (ix ^ e00) & TMASK; iB = (jx ^ e00) & TMASK;
  s.oA0 = (int)(iA & 1u); s.oB0 = (int)(iB & 1u);
  s.lo0 = *(const f4*)(tab + (iA & ~1u)); s.hi0 = *(const f4*)(tab + (iB & ~1u));
  s.wA0 = wx0 * w00; s.wB0 = wx1 * w00;
  iA = (ix ^ e10) & TMASK; iB = (jx ^ e10) & TMASK;
  s.oA1 = (int)(iA & 1u); s.oB1 = (int)(iB & 1u);
  s.lo1 = *(const f4*)(tab + (iA & ~1u)); s.hi1 = *(const f4*)(tab + (iB & ~1u));
  s.wA1 = wx0 * w10; s.wB1 = wx1 * w10;
  iA = (ix ^ e01) & TMASK; iB = (jx ^ e01) & TMASK;
  s.oA2 = (int)(iA & 1u); s.oB2 = (int)(iB & 1u);
  s.lo2 = *(const f4*)(tab + (iA & ~1u)); s.hi2 = *(const f4*)(tab + (iB & ~1u));
  s.wA2 = wx0 * w01; s.wB2 = wx1 * w01;
  iA = (ix ^ e11) & TMASK; iB = (jx ^ e11) & TMASK;
  s.oA3 = (int)(iA & 1u); s.oB3 = (int)(iB & 1u);
  s.lo3 = *(const f4*)(tab + (iA & ~1u)); s.hi3 = *(const f4*)(tab + (iB & ~1u));
  s.wA3 = wx0 * w11; s.wB3 = wx1 * w11;
}

__device__ __forceinline__ void hpair2(f4 lo, f4 hi, int oA, int oB, float wA,
                                       float wB, float& a0, float& a1) {
  float eAx = oA ? lo.z : lo.x, eAy = oA ? lo.w : lo.y;
  float eBx = oB ? hi.z : hi.x, eBy = oB ? hi.w : hi.y;
  a0 = fmaf(wA, eAx, a0); a1 = fmaf(wA, eAy, a1);
  a0 = fmaf(wB, eBx, a0); a1 = fmaf(wB, eBy, a1);
}

__device__ __forceinline__ f2 hash_consume(const HS& s) {
  float a0 = 0.f, a1 = 0.f;
  hpair2(s.lo0, s.hi0, s.oA0, s.oB0, s.wA0, s.wB0, a0, a1);
  hpair2(s.lo1, s.hi1, s.oA1, s.oB1, s.wA1, s.wB1, a0, a1);
  hpair2(s.lo2, s.hi2, s.oA2, s.oB2, s.wA2, s.wB2, a0, a1);
  hpair2(s.lo3, s.hi3, s.oA3, s.oB3, s.wA3, s.wB3, a0, a1);
  f2 r; r.x = a0; r.y = a1;
  return r;
}

// ---- main henc: r14-identical (1 pt/thread, VGPR 32, 83% occupancy) --------
template <int LVL, int MODE>
__device__ __forceinline__ void do_phase(const Params& p,
                                         const f2* __restrict__ emb,
                                         const char* __restrict__ ws, float cx,
                                         float cy, float cz, int pt,
                                         unsigned* lds) {
  f2 r;
  if constexpr (LVL < NGRID) {
    if constexpr (MODE < 2) {
      GB s;
      gridb_issue<LVL>(p, ws, cx, cy, cz, s);
      r = gridb_consume(s);
    } else {
      r = grid_direct<LVL>(p, emb, cx, cy, cz);
    }
  } else {
    if constexpr (MODE == 0) {
      HB s;
      hashb_issue<LVL>(p, ws, cx, cy, cz, s);
      r = hashb_consume(s);
    } else {
      HS s;
      hash_issue<LVL>(p, emb, cx, cy, cz, s);
      r = hash_consume(s);
    }
  }
  lds[pt * 8 + ((LVL & 7) ^ swz(pt))] = packbf(r);
}

template <bool SORTED>
__device__ __forceinline__ void readout(float* __restrict__ out,
                                        const unsigned* lds,
                                        const unsigned* oiLds, int n0, int h,
                                        int tid) {
#pragma unroll
  for (int j = 0; j < 4; ++j) {
    int f = tid + BLK * j;  // f4 index 0..2047
    int pt = f >> 2, k = f & 3;
    int s = swz(pt);
    unsigned u0 = lds[pt * 8 + ((2 * k) ^ s)];
    unsigned u1 = lds[pt * 8 + ((2 * k + 1) ^ s)];
    f4 o4; o4.x = bflo(u0); o4.y = bfhi(u0); o4.z = bflo(u1); o4.w = bfhi(u1);
    size_t base = SORTED ? (size_t)oiLds[pt] * 32 : (size_t)(n0 + pt) * 32;
    __builtin_nontemporal_store(o4, (f4*)(out + base + h * 16 + k * 4));
  }
}

template <int MODE, bool SORTED>
__global__ __launch_bounds__(BLK, 4) void henc(const float* __restrict__ coords,
                                               const f2* __restrict__ emb,
                                               float* __restrict__ out,
                                               const char* __restrict__ ws,
                                               const f4* __restrict__ sorted,
                                               Params p) {
  __shared__ unsigned lds[PTS_PER_BLK * 8];  // 16 KB packed bf16
  __shared__ unsigned oiLds[PTS_PER_BLK];    // 2 KB original indices
  const int tid = (int)threadIdx.x;
  const int n0 = (int)blockIdx.x * PTS_PER_BLK;
  const int pt = tid;

  float cx, cy, cz;
  if constexpr (SORTED) {
    f4 s0 = sorted[n0 + pt];  // perfectly coalesced f4 per lane
    cx = s0.x; cy = s0.y; cz = s0.z;
    oiLds[pt] = __float_as_uint(s0.w);
  } else {
    cx = coords[3 * (n0 + pt) + 0];
    cy = coords[3 * (n0 + pt) + 1];
    cz = coords[3 * (n0 + pt) + 2];
  }

  do_phase<0, MODE>(p, emb, ws, cx, cy, cz, pt, lds);
  do_phase<1, MODE>(p, emb, ws, cx, cy, cz, pt, lds);
  do_phase<2, MODE>(p, emb, ws, cx, cy, cz, pt, lds);
  do_phase<3, MODE>(p, emb, ws, cx, cy, cz, pt, lds);
  do_phase<4, MODE>(p, emb, ws, cx, cy, cz, pt, lds);
  do_phase<5, MODE>(p, emb, ws, cx, cy, cz, pt, lds);
  do_phase<6, MODE>(p, emb, ws, cx, cy, cz, pt, lds);
  do_phase<7, MODE>(p, emb, ws, cx, cy, cz, pt, lds);
  __syncthreads();
  readout<SORTED>(out, lds, oiLds, n0, 0, tid);
  __syncthreads();  // LDS reuse fence

  do_phase<8, MODE>(p, emb, ws, cx, cy, cz, pt, lds);
  do_phase<9, MODE>(p, emb, ws, cx, cy, cz, pt, lds);
  do_phase<10, MODE>(p, emb, ws, cx, cy, cz, pt, lds);
  do_phase<11, MODE>(p, emb, ws, cx, cy, cz, pt, lds);
  do_phase<12, MODE>(p, emb, ws, cx, cy, cz, pt, lds);
  do_phase<13, MODE>(p, emb, ws, cx, cy, cz, pt, lds);
  do_phase<14, MODE>(p, emb, ws, cx, cy, cz, pt, lds);
  do_phase<15, MODE>(p, emb, ws, cx, cy, cz, pt, lds);
  __syncthreads();
  readout<SORTED>(out, lds, oiLds, n0, 1, tid);
}

extern "C" void kernel_launch(void* const* d_in, const int* in_sizes, int n_in,
                              void* d_out, int out_size, void* d_ws,
                              size_t ws_size, hipStream_t stream) {
  const float* coords = (const float*)d_in[0];
  const f2* emb = (const f2*)d_in[1];
  float* out = (float*)d_out;
  char* ws = (char*)d_ws;

  // Replicate Python's level_params() bit-exactly with host libm doubles.
  Params p;
  double b = pow(32.0, 1.0 / 15.0);
  long long cum = 0, cellCum = 0;
  int resMax = 64;
  for (int i = 0; i < NLVL; ++i) {
    int r = (int)floor(16.0 * pow(b, (double)i));
    p.resf[i] = (float)r;
    p.off[i] = (int)cum;
    long long e3 = (long long)(r + 1) * (r + 1) * (r + 1);
    cum += e3 > 524288 ? 524288 : e3;
    if (i < NGRID) {
      p.cellOffB[i] = (int)(cellCum * 32);  // bf16 cell = 32 B
      cellCum += (long long)r * r * r;
      if (i == NGRID - 1) resMax = r;
    }
  }
  long long gridB = ((cellCum * 32 + 63) / 64) * 64;
  for (int h = 0; h < NHASH; ++h)
    p.hOffB[h] = (int)(gridB + (long long)h * (524288 * 4));
  size_t needB = (size_t)gridB;                       // grid-only tier
  size_t needA = (size_t)(gridB + 9LL * 524288 * 4);  // full bf16 tier

  // sort-tier layout (after tables, 256-aligned)
  size_t cntOff = (needA + 255) & ~(size_t)255;
  size_t exclOff = cntOff + (size_t)NBKT * 4;
  size_t bsumOff = exclOff + (size_t)NBKT * 4;
  size_t sortedOff = (bsumOff + 4096 + 255) & ~(size_t)255;
  size_t needS = sortedOff + (size_t)NPTS * 16;  // ~68.5 MB

  int mode = ws_size >= needA ? 0 : (ws_size >= needB ? 1 : 2);
  bool doSort = ws_size >= needS;
  p.cnt = (unsigned*)(ws + cntOff);

  if (mode == 0) {
    // y=16 slice zeroes the sort counters (replaces the memset node)
    int ny = doSort ? NLVL + 1 : NLVL;
    repack_all<<<dim3(524288 / 256, ny), dim3(256), 0, stream>>>(emb, ws, p);
    if (doSort) {
      unsigned* cnt = (unsigned*)(ws + cntOff);
      unsigned* excl = (unsigned*)(ws + exclOff);
      unsigned* bsum = (unsigned*)(ws + bsumOff);
      f4* sorted = (f4*)(ws + sortedOff);
      hist_k<<<dim3(NPTS / 4 / 256), dim3(256), 0, stream>>>(coords, cnt);
      scan1_k<<<dim3(NBKT / 256), dim3(256), 0, stream>>>(cnt, excl, bsum);
      scan2_k<<<dim3(1), dim3(1024), 0, stream>>>(bsum);
      scat_k<<<dim3(NPTS / 4 / 256), dim3(256), 0, stream>>>(coords, excl,
                                                             bsum, sorted);
      henc<0, true><<<dim3(NBLK), dim3(BLK), 0, stream>>>(coords, emb, out, ws,
                                                          sorted, p);
    } else {
      henc<0, false><<<dim3(NBLK), dim3(BLK), 0, stream>>>(coords, emb, out,
                                                           ws, nullptr, p);
    }
  } else if (mode == 1) {
    int bx = (resMax * resMax * resMax + 255) / 256;
    repack_grid<<<dim3(bx, NGRID), dim3(256), 0, stream>>>(emb, ws, p);
    henc<1, false><<<dim3(NBLK), dim3(BLK), 0, stream>>>(coords, emb, out, ws,
                                                         nullptr, p);
  } else {
    henc<2, false><<<dim3(NBLK), dim3(BLK), 0, stream>>>(coords, emb, out, ws,
                                                         nullptr, p);
  }
}